// Round 18
// baseline (486.956 us; speedup 1.0000x reference)
//
#include <hip/hip_runtime.h>
#include <hip/hip_bf16.h>
#include <math.h>

#define B_    8
#define N_    1024
#define D_    1024
#define H_    16
#define DH_   64
#define HID_  4096
#define KD_   512
#define ROWS_ 8192

typedef _Float16 half8 __attribute__((ext_vector_type(8)));
typedef _Float16 half4v __attribute__((ext_vector_type(4)));
typedef float f32x4 __attribute__((ext_vector_type(4)));

// ---------------- reductions ----------------
__device__ __forceinline__ float waveSum(float v) {
#pragma unroll
  for (int off = 32; off > 0; off >>= 1) v += __shfl_down(v, off, 64);
  return v;
}
__device__ __forceinline__ float waveMax(float v) {
#pragma unroll
  for (int off = 32; off > 0; off >>= 1) v = fmaxf(v, __shfl_down(v, off, 64));
  return v;
}

// ---------------- threefry2x32, key=(0,42) ----------------
__device__ __forceinline__ uint32_t rotl32(uint32_t x, int r) { return (x << r) | (x >> (32 - r)); }

__device__ __forceinline__ void threefry_0_42(uint32_t& x0, uint32_t& x1) {
  const uint32_t ks0 = 0u, ks1 = 42u, ks2 = 0x1BD11BDAu ^ 42u;
#define TF_R(r) { x0 += x1; x1 = rotl32(x1, r); x1 ^= x0; }
  x0 += ks0; x1 += ks1;
  TF_R(13) TF_R(15) TF_R(26) TF_R(6)   x0 += ks1; x1 += ks2 + 1u;
  TF_R(17) TF_R(29) TF_R(16) TF_R(24)  x0 += ks2; x1 += ks0 + 2u;
  TF_R(13) TF_R(15) TF_R(26) TF_R(6)   x0 += ks0; x1 += ks1 + 3u;
  TF_R(17) TF_R(29) TF_R(16) TF_R(24)  x0 += ks1; x1 += ks2 + 4u;
  TF_R(13) TF_R(15) TF_R(26) TF_R(6)   x0 += ks2; x1 += ks0 + 5u;
#undef TF_R
}

__device__ __forceinline__ float bits_to_gumbel(uint32_t bits) {
  const float TINY = 1.1754943508222875e-38f;
  float u = __uint_as_float((bits >> 9) | 0x3f800000u) - 1.0f;
  u = u + TINY;
  u = fmaxf(TINY, u);
  return -logf(-logf(u));
}

// jax_threefry_partitionable: bits[j] = y0^y1 of threefry_{0,42}(0, j)
__device__ __forceinline__ float gumbel_at(unsigned j) {
  uint32_t x0 = 0u, x1 = j;
  threefry_0_42(x0, x1);
  return bits_to_gumbel(x0 ^ x1);
}

// ---------------- fused fp32 -> fp16 weight conversion (4 sources, contiguous dest) ----------------
__global__ __launch_bounds__(256) void f2h4_kernel(const float* __restrict__ s0,
                                                   const float* __restrict__ s1,
                                                   const float* __restrict__ s2,
                                                   const float* __restrict__ s3,
                                                   _Float16* __restrict__ out) {
  const int i = blockIdx.x * 256 + threadIdx.x;   // 0..3,145,727 (float4 units)
  const float4* src;
  int off = i;
  if (i < 786432)       { src = (const float4*)s0; }
  else if (i < 1048576) { src = (const float4*)s1; off = i - 786432; }
  else if (i < 2097152) { src = (const float4*)s2; off = i - 1048576; }
  else                  { src = (const float4*)s3; off = i - 2097152; }
  const float4 v = src[off];
  half4v h;
  h[0] = (_Float16)v.x; h[1] = (_Float16)v.y; h[2] = (_Float16)v.z; h[3] = (_Float16)v.w;
  reinterpret_cast<half4v*>(out)[i] = h;
}

// ---------------- LayerNorm -> fp16 out (fp32 or fp16 input) ----------------
template <bool IN_HALF>
__global__ __launch_bounds__(256) void ln_kernel(const void* __restrict__ in,
                                                 const float* __restrict__ w,
                                                 const float* __restrict__ b,
                                                 _Float16* __restrict__ out) {
  __shared__ float sh[4];
  const int row = blockIdx.x;
  const int tid = threadIdx.x;
  float x0, x1, x2, x3;
  if (IN_HALF) {
    const half4v v = reinterpret_cast<const half4v*>((const _Float16*)in + (size_t)row * D_)[tid];
    x0 = (float)v[0]; x1 = (float)v[1]; x2 = (float)v[2]; x3 = (float)v[3];
  } else {
    const float4 v = reinterpret_cast<const float4*>((const float*)in + (size_t)row * D_)[tid];
    x0 = v.x; x1 = v.y; x2 = v.z; x3 = v.w;
  }
  float s = x0 + x1 + x2 + x3;
  s = waveSum(s);
  if ((tid & 63) == 0) sh[tid >> 6] = s;
  __syncthreads();
  const float mean = (sh[0] + sh[1] + sh[2] + sh[3]) * (1.0f / D_);
  __syncthreads();
  const float dx = x0 - mean, dy = x1 - mean, dz = x2 - mean, dw = x3 - mean;
  float q = dx * dx + dy * dy + dz * dz + dw * dw;
  q = waveSum(q);
  if ((tid & 63) == 0) sh[tid >> 6] = q;
  __syncthreads();
  const float rstd = rsqrtf((sh[0] + sh[1] + sh[2] + sh[3]) * (1.0f / D_) + 1e-5f);
  const float4 wv = reinterpret_cast<const float4*>(w)[tid];
  const float4 bv = reinterpret_cast<const float4*>(b)[tid];
  half4v o;
  o[0] = (_Float16)(dx * rstd * wv.x + bv.x);
  o[1] = (_Float16)(dy * rstd * wv.y + bv.y);
  o[2] = (_Float16)(dz * rstd * wv.z + bv.z);
  o[3] = (_Float16)(dw * rstd * wv.w + bv.w);
  reinterpret_cast<half4v*>(out + (size_t)row * D_)[tid] = o;
}

// ---------------- fast GELU: A&S 7.1.26 erf approx, max err 1.5e-7 ----------------
__device__ __forceinline__ float fast_gelu(float x) {
  const float z = fabsf(x) * 0.70710678118654752f;
  const float t = 1.0f / (1.0f + 0.3275911f * z);
  const float poly = t * (0.254829592f + t * (-0.284496736f +
                      t * (1.421413741f + t * (-1.453152027f + t * 1.061405429f))));
  float erfz = 1.0f - poly * __expf(-z * z);
  erfz = copysignf(erfz, x);
  return 0.5f * x * (1.0f + erfz);
}

__device__ __forceinline__ float res_at(const void* p, size_t off, bool rh) {
  return rh ? (float)((const _Float16*)p)[off] : ((const float*)p)[off];
}

#define GLDS16(g, l)                                                             \
  __builtin_amdgcn_global_load_lds((const __attribute__((address_space(1))) void*)(g), \
                                   (__attribute__((address_space(3))) void*)(l), 16, 0, 0)

// ============ 2-phase-wide 8-wave 256x256, BK=64 (R13/R15-best; qkv) ============
template <bool GELU_EP, bool RES, bool RESH, bool OUT_HALF>
__global__ __launch_bounds__(512) void hgemm8w_kernel(const _Float16* __restrict__ A,
                                                      const _Float16* __restrict__ W,
                                                      const float* __restrict__ bias,
                                                      const void* __restrict__ res,
                                                      void* __restrict__ Cout,
                                                      int Nn, int K, int nbx) {
  __shared__ __align__(16) _Float16 Asb[2][2][16 * 512];
  __shared__ __align__(16) _Float16 Bsb[2][2][16 * 512];

  const int tid = threadIdx.x;
  const int lane = tid & 63;
  const int wv = tid >> 6;
  const int wr = wv >> 2, wc = wv & 3;
  const int fr = lane & 15;
  const int k8 = (lane >> 4) << 3;

  const int nwg = (int)gridDim.x;
  const int q8 = nwg >> 3, r8 = nwg & 7;
  const int x = (int)blockIdx.x & 7, idx = (int)blockIdx.x >> 3;
  const int wg = (x < r8 ? x * (q8 + 1) : r8 * (q8 + 1) + (x - r8) * q8) + idx;
  const int m0 = (wg / nbx) * 256, n0 = (wg % nbx) * 256;

  const int KT = K >> 6;

#define STAGE_A(pt, kc, kt)                                                           \
  { _Pragma("unroll") for (int rho = 0; rho < 2; ++rho) {                             \
      const int f = rho * 8 + wv;                                                     \
      GLDS16(A + (size_t)(m0 + f * 16 + fr) * K + (kt) * 64 + (kc) * 32 + k8,         \
             &Asb[pt][kc][f * 512]); } }
#define STAGE_B(pt, kc, kt)                                                           \
  { _Pragma("unroll") for (int rho = 0; rho < 2; ++rho) {                             \
      const int f = rho * 8 + wv;                                                     \
      GLDS16(W + (size_t)(n0 + f * 16 + fr) * K + (kt) * 64 + (kc) * 32 + k8,         \
             &Bsb[pt][kc][f * 512]); } }

  f32x4 acc[8][4];
#pragma unroll
  for (int i = 0; i < 8; ++i)
#pragma unroll
    for (int j = 0; j < 4; ++j) acc[i][j] = (f32x4)0.0f;

  STAGE_A(0, 0, 0); STAGE_B(0, 0, 0);
  STAGE_A(0, 1, 0); STAGE_B(0, 1, 0);
  STAGE_A(1, 0, 1); STAGE_B(1, 0, 1);

  half8 af[4], ag[4], bf[4];
  for (int t = 0; t < KT; ++t) {
    const int p = t & 1;
    if (t == KT - 1) { asm volatile("s_waitcnt vmcnt(0)" ::: "memory"); }
    else             { asm volatile("s_waitcnt vmcnt(4)" ::: "memory"); }
    __builtin_amdgcn_s_barrier();
#pragma unroll
    for (int kc = 0; kc < 2; ++kc) {
#pragma unroll
      for (int i = 0; i < 4; ++i)
        af[i] = *reinterpret_cast<const half8*>(&Asb[p][kc][(wr * 8 + i) * 512 + lane * 8]);
#pragma unroll
      for (int i = 0; i < 4; ++i)
        ag[i] = *reinterpret_cast<const half8*>(&Asb[p][kc][(wr * 8 + 4 + i) * 512 + lane * 8]);
#pragma unroll
      for (int j = 0; j < 4; ++j)
        bf[j] = *reinterpret_cast<const half8*>(&Bsb[p][kc][(wc * 4 + j) * 512 + lane * 8]);
      if (kc == 0) { if (t + 1 < KT) { STAGE_A(p ^ 1, 1, t + 1); STAGE_B(p ^ 1, 1, t + 1); } }
      else         { if (t + 2 < KT) { STAGE_A(p, 0, t + 2);     STAGE_B(p, 0, t + 2); } }
      __builtin_amdgcn_s_barrier();
      asm volatile("s_waitcnt lgkmcnt(0)" ::: "memory");
      __builtin_amdgcn_s_setprio(1);
#pragma unroll
      for (int i = 0; i < 4; ++i)
#pragma unroll
        for (int j = 0; j < 4; ++j)
          acc[i][j] = __builtin_amdgcn_mfma_f32_16x16x32_f16(af[i], bf[j], acc[i][j], 0, 0, 0);
#pragma unroll
      for (int i = 0; i < 4; ++i)
#pragma unroll
        for (int j = 0; j < 4; ++j)
          acc[4 + i][j] = __builtin_amdgcn_mfma_f32_16x16x32_f16(ag[i], bf[j], acc[4 + i][j], 0, 0, 0);
      __builtin_amdgcn_s_setprio(0);
      __builtin_amdgcn_s_barrier();
    }
  }
#undef STAGE_A
#undef STAGE_B

  float bv[4];
#pragma unroll
  for (int nf = 0; nf < 4; ++nf) bv[nf] = bias[n0 + wc * 64 + nf * 16 + fr];
#pragma unroll
  for (int mf = 0; mf < 8; ++mf) {
#pragma unroll
    for (int r = 0; r < 4; ++r) {
      const int row = m0 + wr * 128 + mf * 16 + ((lane >> 4) << 2) + r;
      const size_t ro = (size_t)row * Nn;
#pragma unroll
      for (int nf = 0; nf < 4; ++nf) {
        const int col = n0 + wc * 64 + nf * 16 + fr;
        float u = acc[mf][nf][r] + bv[nf];
        if (GELU_EP) u = fast_gelu(u);
        if (RES) u += res_at(res, ro + col, RESH);
        if (OUT_HALF) ((_Float16*)Cout)[ro + col] = (_Float16)u;
        else          ((float*)Cout)[ro + col] = u;
      }
    }
  }
}

// ============ 128x256 8-wave, counted-vmcnt kc-split FIFO, BK=64 (R17; proj & fc2) ============
template <bool GELU_EP, bool RES, bool RESH, bool OUT_HALF>
__global__ __launch_bounds__(512) void hgemm128_kernel(const _Float16* __restrict__ A,
                                                       const _Float16* __restrict__ W,
                                                       const float* __restrict__ bias,
                                                       const void* __restrict__ res,
                                                       void* __restrict__ Cout,
                                                       int Nn, int K, int nbx) {
  __shared__ __align__(16) _Float16 Ab[2][2][8 * 512];    // 32KB
  __shared__ __align__(16) _Float16 Bb[2][2][16 * 512];   // 64KB

  const int tid = threadIdx.x;
  const int lane = tid & 63;
  const int wv = tid >> 6;
  const int wr = wv >> 2, wc = wv & 3;       // wave = 64x64 out tile
  const int fr = lane & 15;
  const int k8 = (lane >> 4) << 3;

  const int nwg = (int)gridDim.x;
  const int q8 = nwg >> 3, r8 = nwg & 7;
  const int x = (int)blockIdx.x & 7, idx = (int)blockIdx.x >> 3;
  const int wg = (x < r8 ? x * (q8 + 1) : r8 * (q8 + 1) + (x - r8) * q8) + idx;
  const int m0 = (wg / nbx) * 128, n0 = (wg % nbx) * 256;

  const int KT = K >> 6;

#define STAGE_AK(pt, kc, kt)                                                          \
  GLDS16(A + (size_t)(m0 + wv * 16 + fr) * K + (kt) * 64 + (kc) * 32 + k8,            \
         &Ab[pt][kc][wv * 512]);
#define STAGE_BK(pt, kc, kt)                                                          \
  { _Pragma("unroll") for (int u = 0; u < 2; ++u)                                     \
      GLDS16(W + (size_t)(n0 + (u * 8 + wv) * 16 + fr) * K + (kt) * 64 + (kc) * 32 + k8, \
             &Bb[pt][kc][(u * 8 + wv) * 512]); }

  f32x4 acc[4][4];
#pragma unroll
  for (int i = 0; i < 4; ++i)
#pragma unroll
    for (int j = 0; j < 4; ++j) acc[i][j] = (f32x4)0.0f;

  STAGE_AK(0, 0, 0) STAGE_BK(0, 0, 0)
  STAGE_AK(0, 1, 0) STAGE_BK(0, 1, 0)
  STAGE_AK(1, 0, 1) STAGE_BK(1, 0, 1)

  half8 af[4], bf[4];
  for (int t = 0; t < KT; ++t) {
    const int p = t & 1;
    if (t == KT - 1) { asm volatile("s_waitcnt vmcnt(0)" ::: "memory"); }
    else             { asm volatile("s_waitcnt vmcnt(3)" ::: "memory"); }
    __builtin_amdgcn_s_barrier();
#pragma unroll
    for (int kc = 0; kc < 2; ++kc) {
#pragma unroll
      for (int i = 0; i < 4; ++i)
        af[i] = *reinterpret_cast<const half8*>(&Ab[p][kc][(wr * 4 + i) * 512 + lane * 8]);
#pragma unroll
      for (int j = 0; j < 4; ++j)
        bf[j] = *reinterpret_cast<const half8*>(&Bb[p][kc][(wc * 4 + j) * 512 + lane * 8]);
      if (kc == 0) { if (t + 1 < KT) { STAGE_AK(p ^ 1, 1, t + 1) STAGE_BK(p ^ 1, 1, t + 1) } }
      else         { if (t + 2 < KT) { STAGE_AK(p, 0, t + 2)     STAGE_BK(p, 0, t + 2) } }
      __builtin_amdgcn_s_barrier();
      asm volatile("s_waitcnt lgkmcnt(0)" ::: "memory");
      __builtin_amdgcn_s_setprio(1);
#pragma unroll
      for (int i = 0; i < 4; ++i)
#pragma unroll
        for (int j = 0; j < 4; ++j)
          acc[i][j] = __builtin_amdgcn_mfma_f32_16x16x32_f16(af[i], bf[j], acc[i][j], 0, 0, 0);
      __builtin_amdgcn_s_setprio(0);
      __builtin_amdgcn_s_barrier();
    }
  }
#undef STAGE_AK
#undef STAGE_BK

  float bv[4];
#pragma unroll
  for (int nf = 0; nf < 4; ++nf) bv[nf] = bias[n0 + wc * 64 + nf * 16 + fr];
#pragma unroll
  for (int mf = 0; mf < 4; ++mf) {
#pragma unroll
    for (int r = 0; r < 4; ++r) {
      const int row = m0 + wr * 64 + mf * 16 + ((lane >> 4) << 2) + r;
      const size_t ro = (size_t)row * Nn;
#pragma unroll
      for (int nf = 0; nf < 4; ++nf) {
        const int col = n0 + wc * 64 + nf * 16 + fr;
        float u = acc[mf][nf][r] + bv[nf];
        if (GELU_EP) u = fast_gelu(u);
        if (RES) u += res_at(res, ro + col, RESH);
        if (OUT_HALF) ((_Float16*)Cout)[ro + col] = (_Float16)u;
        else          ((float*)Cout)[ro + col] = u;
      }
    }
  }
}

// ============ EXPERIMENT: 128x256 8-wave, BK=32, 48KB LDS -> 2 blocks/CU (fc1) ============
// Per K-tile(32): vmcnt(3) [t done, t+1 in flight] -> barrier -> ds_read 8 frags -> lgkmcnt(0)
// -> barrier [all reads of buf p done] -> stage t+2 into buf p -> 16 MFMA.
// __launch_bounds__(512,4) caps VGPR at 128 so 2 blocks co-reside: sibling block's MFMA
// covers this block's barrier/drain stalls (m114 overlap, now with preserved B-reuse).
template <bool GELU_EP, bool RES, bool RESH, bool OUT_HALF>
__global__ __launch_bounds__(512, 4) void hgemm128b_kernel(const _Float16* __restrict__ A,
                                                           const _Float16* __restrict__ W,
                                                           const float* __restrict__ bias,
                                                           const void* __restrict__ res,
                                                           void* __restrict__ Cout,
                                                           int Nn, int K, int nbx) {
  __shared__ __align__(16) _Float16 Ab[2][8 * 512];    // 16KB
  __shared__ __align__(16) _Float16 Bb[2][16 * 512];   // 32KB

  const int tid = threadIdx.x;
  const int lane = tid & 63;
  const int wv = tid >> 6;
  const int wr = wv >> 2, wc = wv & 3;       // wave = 64x64 out tile
  const int fr = lane & 15;
  const int k8 = (lane >> 4) << 3;

  const int nwg = (int)gridDim.x;
  const int q8 = nwg >> 3, r8 = nwg & 7;
  const int x = (int)blockIdx.x & 7, idx = (int)blockIdx.x >> 3;
  const int wg = (x < r8 ? x * (q8 + 1) : r8 * (q8 + 1) + (x - r8) * q8) + idx;
  const int m0 = (wg / nbx) * 128, n0 = (wg % nbx) * 256;

  const int KT = K >> 5;   // K-tiles of 32

#define STG(pt, kt)                                                                   \
  GLDS16(A + (size_t)(m0 + wv * 16 + fr) * K + (kt) * 32 + k8, &Ab[pt][wv * 512]);    \
  { _Pragma("unroll") for (int u = 0; u < 2; ++u)                                     \
      GLDS16(W + (size_t)(n0 + (u * 8 + wv) * 16 + fr) * K + (kt) * 32 + k8,          \
             &Bb[pt][(u * 8 + wv) * 512]); }

  f32x4 acc[4][4];
#pragma unroll
  for (int i = 0; i < 4; ++i)
#pragma unroll
    for (int j = 0; j < 4; ++j) acc[i][j] = (f32x4)0.0f;

  STG(0, 0)
  STG(1, 1)

  half8 af[4], bf[4];
  for (int t = 0; t < KT; ++t) {
    const int p = t & 1;
    if (t >= KT - 1) { asm volatile("s_waitcnt vmcnt(0)" ::: "memory"); }
    else             { asm volatile("s_waitcnt vmcnt(3)" ::: "memory"); }
    __builtin_amdgcn_s_barrier();
#pragma unroll
    for (int i = 0; i < 4; ++i)
      af[i] = *reinterpret_cast<const half8*>(&Ab[p][(wr * 4 + i) * 512 + lane * 8]);
#pragma unroll
    for (int j = 0; j < 4; ++j)
      bf[j] = *reinterpret_cast<const half8*>(&Bb[p][(wc * 4 + j) * 512 + lane * 8]);
    asm volatile("s_waitcnt lgkmcnt(0)" ::: "memory");
    __builtin_amdgcn_s_barrier();                 // all waves done reading buf p
    if (t + 2 < KT) { STG(p, t + 2) }             // safe: overwrites fully-consumed buf
    __builtin_amdgcn_s_setprio(1);
#pragma unroll
    for (int i = 0; i < 4; ++i)
#pragma unroll
      for (int j = 0; j < 4; ++j)
        acc[i][j] = __builtin_amdgcn_mfma_f32_16x16x32_f16(af[i], bf[j], acc[i][j], 0, 0, 0);
    __builtin_amdgcn_s_setprio(0);
  }
#undef STG

  float bv[4];
#pragma unroll
  for (int nf = 0; nf < 4; ++nf) bv[nf] = bias[n0 + wc * 64 + nf * 16 + fr];
#pragma unroll
  for (int mf = 0; mf < 4; ++mf) {
#pragma unroll
    for (int r = 0; r < 4; ++r) {
      const int row = m0 + wr * 64 + mf * 16 + ((lane >> 4) << 2) + r;
      const size_t ro = (size_t)row * Nn;
#pragma unroll
      for (int nf = 0; nf < 4; ++nf) {
        const int col = n0 + wc * 64 + nf * 16 + fr;
        float u = acc[mf][nf][r] + bv[nf];
        if (GELU_EP) u = fast_gelu(u);
        if (RES) u += res_at(res, ro + col, RESH);
        if (OUT_HALF) ((_Float16*)Cout)[ro + col] = (_Float16)u;
        else          ((float*)Cout)[ro + col] = u;
      }
    }
  }
}

// ---------------- MFMA flash attention, QBLK=128, 8 waves (R15-best) ----------------
__global__ __launch_bounds__(512) void mattn_kernel(const _Float16* __restrict__ qkv,
                                                    _Float16* __restrict__ ctx) {
  __shared__ __align__(16) _Float16 Ks[64][72];
  __shared__ __align__(16) _Float16 Vt[64][72];
  __shared__ __align__(16) _Float16 Ps[8][16][72];
  const int qt = blockIdx.x, h = blockIdx.y, b = blockIdx.z;
  const int tid = threadIdx.x;
  const int lane = tid & 63;
  const int w = tid >> 6;
  const int l15 = lane & 15;
  const int koff = (lane >> 4) * 8;

  const size_t qrow = (size_t)b * N_ + qt * 128 + w * 16 + l15;
  half8 qf0 = *reinterpret_cast<const half8*>(qkv + qrow * 3072 + h * 64 + koff);
  half8 qf1 = *reinterpret_cast<const half8*>(qkv + qrow * 3072 + h * 64 + 32 + koff);
  qf0 *= (_Float16)0.125f;
  qf1 *= (_Float16)0.125f;

  const int skey = tid >> 2;                  // valid for tid<256
  const int sch = (tid & 3) * 16;
  const int vcol = skey ^ ((tid & 3) << 4);

  float m_i[4], l_i[4];
  f32x4 oacc[4];
#pragma unroll
  for (int r = 0; r < 4; ++r) { m_i[r] = -3.0e38f; l_i[r] = 0.0f; }
#pragma unroll
  for (int jb = 0; jb < 4; ++jb) oacc[jb] = (f32x4)0.0f;

  for (int kt = 0; kt < 16; ++kt) {
    __syncthreads();
    if (tid < 256) {
      const _Float16* krow = qkv + ((size_t)b * N_ + kt * 64 + skey) * 3072 + 1024 + h * 64 + sch;
      half8 k0 = *reinterpret_cast<const half8*>(krow);
      half8 k1 = *reinterpret_cast<const half8*>(krow + 8);
      half8 v0 = *reinterpret_cast<const half8*>(krow + 1024);
      half8 v1 = *reinterpret_cast<const half8*>(krow + 1032);
      *reinterpret_cast<half8*>(&Ks[skey][sch]) = k0;
      *reinterpret_cast<half8*>(&Ks[skey][sch + 8]) = k1;
#pragma unroll
      for (int j = 0; j < 8; ++j) {
        Vt[sch + j][vcol] = v0[j];
        Vt[sch + 8 + j][vcol] = v1[j];
      }
    }
    __syncthreads();

    f32x4 sacc[4];
#pragma unroll
    for (int jb = 0; jb < 4; ++jb) sacc[jb] = (f32x4)0.0f;
#pragma unroll
    for (int jb = 0; jb < 4; ++jb) {
      half8 kfa = *reinterpret_cast<const half8*>(&Ks[jb * 16 + l15][koff]);
      half8 kfb = *reinterpret_cast<const half8*>(&Ks[jb * 16 + l15][32 + koff]);
      sacc[jb] = __builtin_amdgcn_mfma_f32_16x16x32_f16(qf0, kfa, sacc[jb], 0, 0, 0);
      sacc[jb] = __builtin_amdgcn_mfma_f32_16x16x32_f16(qf1, kfb, sacc[jb], 0, 0, 0);
    }

    float p[4][4];
#pragma unroll
    for (int r = 0; r < 4; ++r) {
      float mx = fmaxf(fmaxf(sacc[0][r], sacc[1][r]), fmaxf(sacc[2][r], sacc[3][r]));
#pragma unroll
      for (int mk = 1; mk < 16; mk <<= 1) mx = fmaxf(mx, __shfl_xor(mx, mk, 64));
      const float nm = fmaxf(m_i[r], mx);
      const float scale = __expf(m_i[r] - nm);
      float rs = 0.0f;
#pragma unroll
      for (int jb = 0; jb < 4; ++jb) { p[jb][r] = __expf(sacc[jb][r] - nm); rs += p[jb][r]; }
#pragma unroll
      for (int mk = 1; mk < 16; mk <<= 1) rs += __shfl_xor(rs, mk, 64);
      l_i[r] = l_i[r] * scale + rs;
      m_i[r] = nm;
#pragma unroll
      for (int jb = 0; jb < 4; ++jb) oacc[jb][r] *= scale;
    }

#pragma unroll
    for (int jb = 0; jb < 4; ++jb)
#pragma unroll
      for (int r = 0; r < 4; ++r)
        Ps[w][(lane >> 4) * 4 + r][jb * 16 + l15] = (_Float16)p[jb][r];

    half8 pf0 = *reinterpret_cast<const half8*>(&Ps[w][l15][koff]);
    half8 pf1 = *reinterpret_cast<const half8*>(&Ps[w][l15][32 + koff]);
#pragma unroll
    for (int jb = 0; jb < 4; ++jb) {
      half8 vf0 = *reinterpret_cast<const half8*>(&Vt[jb * 16 + l15][koff ^ (jb << 4)]);
      half8 vf1 = *reinterpret_cast<const half8*>(&Vt[jb * 16 + l15][(32 + koff) ^ (jb << 4)]);
      oacc[jb] = __builtin_amdgcn_mfma_f32_16x16x32_f16(pf0, vf0, oacc[jb], 0, 0, 0);
      oacc[jb] = __builtin_amdgcn_mfma_f32_16x16x32_f16(pf1, vf1, oacc[jb], 0, 0, 0);
    }
  }

#pragma unroll
  for (int jb = 0; jb < 4; ++jb)
#pragma unroll
    for (int r = 0; r < 4; ++r) {
      const size_t orow = (size_t)b * N_ + qt * 128 + w * 16 + (lane >> 4) * 4 + r;
      ctx[orow * 1024 + h * 64 + jb * 16 + l15] = (_Float16)(oacc[jb][r] / l_i[r]);
    }
}

// ---------------- score: mp[row] = dot(h_fp16[row], lin_w) ----------------
__global__ __launch_bounds__(256) void score_kernel(const _Float16* __restrict__ hbuf,
                                                    const float* __restrict__ lw,
                                                    float* __restrict__ mp) {
  __shared__ float sh[4];
  const int row = blockIdx.x, tid = threadIdx.x;
  const half4v v = reinterpret_cast<const half4v*>(hbuf + (size_t)row * D_)[tid];
  const float4 w = reinterpret_cast<const float4*>(lw)[tid];
  float s = (float)v[0] * w.x + (float)v[1] * w.y + (float)v[2] * w.z + (float)v[3] * w.w;
  s = waveSum(s);
  if ((tid & 63) == 0) sh[tid >> 6] = s;
  __syncthreads();
  if (tid == 0) mp[row] = sh[0] + sh[1] + sh[2] + sh[3];
}

// ---------------- lse over n of 2*(mp+g), gumbel computed inline ----------------
__global__ __launch_bounds__(256) void lse_kernel(const float* __restrict__ mp,
                                                  float* __restrict__ lse) {
  __shared__ float sh[4];
  const int row = blockIdx.x;          // k*8+b
  const int b = row & 7;
  const int tid = threadIdx.x;
  const unsigned j0 = (unsigned)row * 1024u + (unsigned)tid * 4u;
  const float4 mv = reinterpret_cast<const float4*>(mp + b * 1024)[tid];
  const float l0 = 2.0f * (gumbel_at(j0 + 0) + mv.x);
  const float l1 = 2.0f * (gumbel_at(j0 + 1) + mv.y);
  const float l2 = 2.0f * (gumbel_at(j0 + 2) + mv.z);
  const float l3 = 2.0f * (gumbel_at(j0 + 3) + mv.w);
  float mx = fmaxf(fmaxf(l0, l1), fmaxf(l2, l3));
  mx = waveMax(mx);
  if ((tid & 63) == 0) sh[tid >> 6] = mx;
  __syncthreads();
  mx = fmaxf(fmaxf(sh[0], sh[1]), fmaxf(sh[2], sh[3]));
  __syncthreads();
  float se = expf(l0 - mx) + expf(l1 - mx) + expf(l2 - mx) + expf(l3 - mx);
  se = waveSum(se);
  if ((tid & 63) == 0) sh[tid >> 6] = se;
  __syncthreads();
  if (tid == 0) lse[row] = mx + logf(sh[0] + sh[1] + sh[2] + sh[3]);
}

// ---------------- z two-stage, gumbel recomputed inline ----------------
__global__ __launch_bounds__(256) void zpart_kernel(const float* __restrict__ lse,
                                                    float* __restrict__ pb) {
  const int idx = blockIdx.x * 256 + threadIdx.x;   // b*1024+n
  const int kc = blockIdx.y;                        // 0..15
  const int b = idx >> 10;
  float best = -3.0e38f;
#pragma unroll 4
  for (int k = kc * 32; k < kc * 32 + 32; ++k) {
    const float gv = gumbel_at((unsigned)k * (unsigned)ROWS_ + (unsigned)idx);
    best = fmaxf(best, 2.0f * gv - lse[k * 8 + b]);
  }
  pb[(size_t)kc * ROWS_ + idx] = best;
}

__global__ __launch_bounds__(256) void zfin_kernel(const float* __restrict__ pb,
                                                   const float* __restrict__ mp,
                                                   float* __restrict__ z) {
  const int idx = blockIdx.x * 256 + threadIdx.x;
  float best = -3.0e38f;
#pragma unroll
  for (int kc = 0; kc < 16; ++kc) best = fmaxf(best, pb[(size_t)kc * ROWS_ + idx]);
  z[idx] = expf(2.0f * mp[idx] + best);
}

extern "C" void kernel_launch(void* const* d_in, const int* in_sizes, int n_in,
                              void* d_out, int out_size, void* d_ws, size_t ws_size,
                              hipStream_t stream) {
  (void)in_sizes; (void)n_in; (void)out_size; (void)ws_size;
  const float* f      = (const float*)d_in[0];
  const float* qkv_w  = (const float*)d_in[2];
  const float* qkv_b  = (const float*)d_in[3];
  const float* proj_w = (const float*)d_in[4];
  const float* proj_b = (const float*)d_in[5];
  const float* ln1_w  = (const float*)d_in[6];
  const float* ln1_b  = (const float*)d_in[7];
  const float* ln2_w  = (const float*)d_in[8];
  const float* ln2_b  = (const float*)d_in[9];
  const float* fc1_w  = (const float*)d_in[10];
  const float* fc1_b  = (const float*)d_in[11];
  const float* fc2_w  = (const float*)d_in[12];
  const float* fc2_b  = (const float*)d_in[13];
  const float* lin_w  = (const float*)d_in[14];
  float* out = (float*)d_out;

  // -------- workspace (f32 offsets; peak ~35.8M f32 = 143 MB) --------
  float* ws = (float*)d_ws;
  _Float16* wh = (_Float16*)d_ws;
  _Float16* QKVWH  = wh;                        // 3,145,728 h
  _Float16* PROJWH = wh + 3145728;              // 1,048,576 h
  _Float16* FC1WH  = wh + 4194304;              // 4,194,304 h
  _Float16* FC2WH  = wh + 8388608;              // 4,194,304 h -> ends f32 6,291,456
  float* MP  = ws + 6291456;                    // 8192
  float* LSE = ws + 6299648;                    // 4096
  _Float16* XH   = (_Float16*)(ws + 6303744);   // 8,388,608 h  -> ends 10,498,048
  _Float16* QKVH = (_Float16*)(ws + 10498048);  // 25,165,824 h (dead after attn)
  _Float16* CTXH = (_Float16*)(ws + 23080960);  // 8,388,608 h (dead after proj)
  _Float16* YH   = (_Float16*)(ws + 10498048);  // 33,554,432 h (reuses QKVH+CTXH)
  _Float16* F1H  = (_Float16*)(ws + 27275264);  // 8,388,608 h  -> ends 31,469,568
  _Float16* HbufH = (_Float16*)(ws + 31469568); // 8,388,608 h  -> ends 35,663,872
  float* PB   = ws + 35663872;                  // 131,072 f32 -> ends 35,794,944

  // fused weight conversion: 4 sources -> contiguous fp16 block (one launch)
  f2h4_kernel<<<12288, 256, 0, stream>>>(qkv_w, proj_w, fc1_w, fc2_w, QKVWH);

  ln_kernel<false><<<ROWS_, 256, 0, stream>>>(f, ln1_w, ln1_b, XH);
  // qkv: M=8192 N=3072 K=1024 -> 256x256, 384 blocks (control)
  hgemm8w_kernel<false, false, false, true><<<384, 512, 0, stream>>>(XH, QKVWH, qkv_b, nullptr, QKVH, 3072, 1024, 12);
  // attention: QBLK=128, 8 waves, 1024 blocks
  mattn_kernel<<<dim3(8, 16, 8), 512, 0, stream>>>(QKVH, CTXH);
  // proj: 128x256, 256 blocks; res = f (fp32), out fp16
  hgemm128_kernel<false, true, false, true><<<256, 512, 0, stream>>>(CTXH, PROJWH, proj_b, f, F1H, 1024, 1024, 4);
  ln_kernel<true><<<ROWS_, 256, 0, stream>>>(F1H, ln2_w, ln2_b, XH);
  // fc1 (EXPERIMENT): 128x256 BK=32 2-blocks/CU, 64x16 = 1024 blocks
  hgemm128b_kernel<true, false, false, true><<<1024, 512, 0, stream>>>(XH, FC1WH, fc1_b, nullptr, YH, 4096, 1024, 16);
  // fc2: 128x256, 256 blocks; res = F1H (fp16), out fp16
  hgemm128_kernel<false, true, true, true><<<256, 512, 0, stream>>>(YH, FC2WH, fc2_b, F1H, HbufH, 1024, 4096, 4);
  score_kernel<<<ROWS_, 256, 0, stream>>>(HbufH, lin_w, MP);
  lse_kernel<<<KD_ * B_, 256, 0, stream>>>(MP, LSE);
  zpart_kernel<<<dim3(ROWS_ / 256, 16), 256, 0, stream>>>(LSE, PB);
  zfin_kernel<<<ROWS_ / 256, 256, 0, stream>>>(PB, MP, out);
}

// Round 19
// 473.039 us; speedup vs baseline: 1.0294x; 1.0294x over previous
//
#include <hip/hip_runtime.h>
#include <hip/hip_bf16.h>
#include <math.h>

#define B_    8
#define N_    1024
#define D_    1024
#define H_    16
#define DH_   64
#define HID_  4096
#define KD_   512
#define ROWS_ 8192

typedef _Float16 half8 __attribute__((ext_vector_type(8)));
typedef _Float16 half4v __attribute__((ext_vector_type(4)));
typedef float f32x4 __attribute__((ext_vector_type(4)));

// ---------------- reductions ----------------
__device__ __forceinline__ float waveSum(float v) {
#pragma unroll
  for (int off = 32; off > 0; off >>= 1) v += __shfl_down(v, off, 64);
  return v;
}
__device__ __forceinline__ float waveMax(float v) {
#pragma unroll
  for (int off = 32; off > 0; off >>= 1) v = fmaxf(v, __shfl_down(v, off, 64));
  return v;
}

// ---------------- threefry2x32, key=(0,42) ----------------
__device__ __forceinline__ uint32_t rotl32(uint32_t x, int r) { return (x << r) | (x >> (32 - r)); }

__device__ __forceinline__ void threefry_0_42(uint32_t& x0, uint32_t& x1) {
  const uint32_t ks0 = 0u, ks1 = 42u, ks2 = 0x1BD11BDAu ^ 42u;
#define TF_R(r) { x0 += x1; x1 = rotl32(x1, r); x1 ^= x0; }
  x0 += ks0; x1 += ks1;
  TF_R(13) TF_R(15) TF_R(26) TF_R(6)   x0 += ks1; x1 += ks2 + 1u;
  TF_R(17) TF_R(29) TF_R(16) TF_R(24)  x0 += ks2; x1 += ks0 + 2u;
  TF_R(13) TF_R(15) TF_R(26) TF_R(6)   x0 += ks0; x1 += ks1 + 3u;
  TF_R(17) TF_R(29) TF_R(16) TF_R(24)  x0 += ks1; x1 += ks2 + 4u;
  TF_R(13) TF_R(15) TF_R(26) TF_R(6)   x0 += ks2; x1 += ks0 + 5u;
#undef TF_R
}

__device__ __forceinline__ float bits_to_gumbel(uint32_t bits) {
  const float TINY = 1.1754943508222875e-38f;
  float u = __uint_as_float((bits >> 9) | 0x3f800000u) - 1.0f;
  u = u + TINY;
  u = fmaxf(TINY, u);
  return -logf(-logf(u));
}

// jax_threefry_partitionable: bits[j] = y0^y1 of threefry_{0,42}(0, j)
__device__ __forceinline__ float gumbel_at(unsigned j) {
  uint32_t x0 = 0u, x1 = j;
  threefry_0_42(x0, x1);
  return bits_to_gumbel(x0 ^ x1);
}

// ---------------- fused fp32 -> fp16 weight conversion (4 sources, contiguous dest) ----------------
__global__ __launch_bounds__(256) void f2h4_kernel(const float* __restrict__ s0,
                                                   const float* __restrict__ s1,
                                                   const float* __restrict__ s2,
                                                   const float* __restrict__ s3,
                                                   _Float16* __restrict__ out) {
  const int i = blockIdx.x * 256 + threadIdx.x;   // 0..3,145,727 (float4 units)
  const float4* src;
  int off = i;
  if (i < 786432)       { src = (const float4*)s0; }
  else if (i < 1048576) { src = (const float4*)s1; off = i - 786432; }
  else if (i < 2097152) { src = (const float4*)s2; off = i - 1048576; }
  else                  { src = (const float4*)s3; off = i - 2097152; }
  const float4 v = src[off];
  half4v h;
  h[0] = (_Float16)v.x; h[1] = (_Float16)v.y; h[2] = (_Float16)v.z; h[3] = (_Float16)v.w;
  reinterpret_cast<half4v*>(out)[i] = h;
}

// ---------------- LayerNorm -> fp16 out (fp32 or fp16 input) ----------------
template <bool IN_HALF>
__global__ __launch_bounds__(256) void ln_kernel(const void* __restrict__ in,
                                                 const float* __restrict__ w,
                                                 const float* __restrict__ b,
                                                 _Float16* __restrict__ out) {
  __shared__ float sh[4];
  const int row = blockIdx.x;
  const int tid = threadIdx.x;
  float x0, x1, x2, x3;
  if (IN_HALF) {
    const half4v v = reinterpret_cast<const half4v*>((const _Float16*)in + (size_t)row * D_)[tid];
    x0 = (float)v[0]; x1 = (float)v[1]; x2 = (float)v[2]; x3 = (float)v[3];
  } else {
    const float4 v = reinterpret_cast<const float4*>((const float*)in + (size_t)row * D_)[tid];
    x0 = v.x; x1 = v.y; x2 = v.z; x3 = v.w;
  }
  float s = x0 + x1 + x2 + x3;
  s = waveSum(s);
  if ((tid & 63) == 0) sh[tid >> 6] = s;
  __syncthreads();
  const float mean = (sh[0] + sh[1] + sh[2] + sh[3]) * (1.0f / D_);
  __syncthreads();
  const float dx = x0 - mean, dy = x1 - mean, dz = x2 - mean, dw = x3 - mean;
  float q = dx * dx + dy * dy + dz * dz + dw * dw;
  q = waveSum(q);
  if ((tid & 63) == 0) sh[tid >> 6] = q;
  __syncthreads();
  const float rstd = rsqrtf((sh[0] + sh[1] + sh[2] + sh[3]) * (1.0f / D_) + 1e-5f);
  const float4 wv = reinterpret_cast<const float4*>(w)[tid];
  const float4 bv = reinterpret_cast<const float4*>(b)[tid];
  half4v o;
  o[0] = (_Float16)(dx * rstd * wv.x + bv.x);
  o[1] = (_Float16)(dy * rstd * wv.y + bv.y);
  o[2] = (_Float16)(dz * rstd * wv.z + bv.z);
  o[3] = (_Float16)(dw * rstd * wv.w + bv.w);
  reinterpret_cast<half4v*>(out + (size_t)row * D_)[tid] = o;
}

// ---------------- fast GELU: A&S 7.1.26 erf approx, max err 1.5e-7 ----------------
__device__ __forceinline__ float fast_gelu(float x) {
  const float z = fabsf(x) * 0.70710678118654752f;
  const float t = 1.0f / (1.0f + 0.3275911f * z);
  const float poly = t * (0.254829592f + t * (-0.284496736f +
                      t * (1.421413741f + t * (-1.453152027f + t * 1.061405429f))));
  float erfz = 1.0f - poly * __expf(-z * z);
  erfz = copysignf(erfz, x);
  return 0.5f * x * (1.0f + erfz);
}

__device__ __forceinline__ float res_at(const void* p, size_t off, bool rh) {
  return rh ? (float)((const _Float16*)p)[off] : ((const float*)p)[off];
}

#define GLDS16(g, l)                                                             \
  __builtin_amdgcn_global_load_lds((const __attribute__((address_space(1))) void*)(g), \
                                   (__attribute__((address_space(3))) void*)(l), 16, 0, 0)

// ============ 2-phase-wide 8-wave 256x256, BK=64 (best; qkv & fc1) ============
template <bool GELU_EP, bool RES, bool RESH, bool OUT_HALF>
__global__ __launch_bounds__(512) void hgemm8w_kernel(const _Float16* __restrict__ A,
                                                      const _Float16* __restrict__ W,
                                                      const float* __restrict__ bias,
                                                      const void* __restrict__ res,
                                                      void* __restrict__ Cout,
                                                      int Nn, int K, int nbx) {
  __shared__ __align__(16) _Float16 Asb[2][2][16 * 512];
  __shared__ __align__(16) _Float16 Bsb[2][2][16 * 512];

  const int tid = threadIdx.x;
  const int lane = tid & 63;
  const int wv = tid >> 6;
  const int wr = wv >> 2, wc = wv & 3;
  const int fr = lane & 15;
  const int k8 = (lane >> 4) << 3;

  const int nwg = (int)gridDim.x;
  const int q8 = nwg >> 3, r8 = nwg & 7;
  const int x = (int)blockIdx.x & 7, idx = (int)blockIdx.x >> 3;
  const int wg = (x < r8 ? x * (q8 + 1) : r8 * (q8 + 1) + (x - r8) * q8) + idx;
  const int m0 = (wg / nbx) * 256, n0 = (wg % nbx) * 256;

  const int KT = K >> 6;

#define STAGE_A(pt, kc, kt)                                                           \
  { _Pragma("unroll") for (int rho = 0; rho < 2; ++rho) {                             \
      const int f = rho * 8 + wv;                                                     \
      GLDS16(A + (size_t)(m0 + f * 16 + fr) * K + (kt) * 64 + (kc) * 32 + k8,         \
             &Asb[pt][kc][f * 512]); } }
#define STAGE_B(pt, kc, kt)                                                           \
  { _Pragma("unroll") for (int rho = 0; rho < 2; ++rho) {                             \
      const int f = rho * 8 + wv;                                                     \
      GLDS16(W + (size_t)(n0 + f * 16 + fr) * K + (kt) * 64 + (kc) * 32 + k8,         \
             &Bsb[pt][kc][f * 512]); } }

  f32x4 acc[8][4];
#pragma unroll
  for (int i = 0; i < 8; ++i)
#pragma unroll
    for (int j = 0; j < 4; ++j) acc[i][j] = (f32x4)0.0f;

  STAGE_A(0, 0, 0); STAGE_B(0, 0, 0);
  STAGE_A(0, 1, 0); STAGE_B(0, 1, 0);
  STAGE_A(1, 0, 1); STAGE_B(1, 0, 1);

  half8 af[4], ag[4], bf[4];
  for (int t = 0; t < KT; ++t) {
    const int p = t & 1;
    if (t == KT - 1) { asm volatile("s_waitcnt vmcnt(0)" ::: "memory"); }
    else             { asm volatile("s_waitcnt vmcnt(4)" ::: "memory"); }
    __builtin_amdgcn_s_barrier();
#pragma unroll
    for (int kc = 0; kc < 2; ++kc) {
#pragma unroll
      for (int i = 0; i < 4; ++i)
        af[i] = *reinterpret_cast<const half8*>(&Asb[p][kc][(wr * 8 + i) * 512 + lane * 8]);
#pragma unroll
      for (int i = 0; i < 4; ++i)
        ag[i] = *reinterpret_cast<const half8*>(&Asb[p][kc][(wr * 8 + 4 + i) * 512 + lane * 8]);
#pragma unroll
      for (int j = 0; j < 4; ++j)
        bf[j] = *reinterpret_cast<const half8*>(&Bsb[p][kc][(wc * 4 + j) * 512 + lane * 8]);
      if (kc == 0) { if (t + 1 < KT) { STAGE_A(p ^ 1, 1, t + 1); STAGE_B(p ^ 1, 1, t + 1); } }
      else         { if (t + 2 < KT) { STAGE_A(p, 0, t + 2);     STAGE_B(p, 0, t + 2); } }
      __builtin_amdgcn_s_barrier();
      asm volatile("s_waitcnt lgkmcnt(0)" ::: "memory");
      __builtin_amdgcn_s_setprio(1);
#pragma unroll
      for (int i = 0; i < 4; ++i)
#pragma unroll
        for (int j = 0; j < 4; ++j)
          acc[i][j] = __builtin_amdgcn_mfma_f32_16x16x32_f16(af[i], bf[j], acc[i][j], 0, 0, 0);
#pragma unroll
      for (int i = 0; i < 4; ++i)
#pragma unroll
        for (int j = 0; j < 4; ++j)
          acc[4 + i][j] = __builtin_amdgcn_mfma_f32_16x16x32_f16(ag[i], bf[j], acc[4 + i][j], 0, 0, 0);
      __builtin_amdgcn_s_setprio(0);
      __builtin_amdgcn_s_barrier();
    }
  }
#undef STAGE_A
#undef STAGE_B

  float bv[4];
#pragma unroll
  for (int nf = 0; nf < 4; ++nf) bv[nf] = bias[n0 + wc * 64 + nf * 16 + fr];
#pragma unroll
  for (int mf = 0; mf < 8; ++mf) {
#pragma unroll
    for (int r = 0; r < 4; ++r) {
      const int row = m0 + wr * 128 + mf * 16 + ((lane >> 4) << 2) + r;
      const size_t ro = (size_t)row * Nn;
#pragma unroll
      for (int nf = 0; nf < 4; ++nf) {
        const int col = n0 + wc * 64 + nf * 16 + fr;
        float u = acc[mf][nf][r] + bv[nf];
        if (GELU_EP) u = fast_gelu(u);
        if (RES) u += res_at(res, ro + col, RESH);
        if (OUT_HALF) ((_Float16*)Cout)[ro + col] = (_Float16)u;
        else          ((float*)Cout)[ro + col] = u;
      }
    }
  }
}

// ============ 128x256 8-wave, counted-vmcnt kc-split FIFO, BK=64 (proj & fc2) ============
template <bool GELU_EP, bool RES, bool RESH, bool OUT_HALF>
__global__ __launch_bounds__(512) void hgemm128_kernel(const _Float16* __restrict__ A,
                                                       const _Float16* __restrict__ W,
                                                       const float* __restrict__ bias,
                                                       const void* __restrict__ res,
                                                       void* __restrict__ Cout,
                                                       int Nn, int K, int nbx) {
  __shared__ __align__(16) _Float16 Ab[2][2][8 * 512];    // 32KB
  __shared__ __align__(16) _Float16 Bb[2][2][16 * 512];   // 64KB

  const int tid = threadIdx.x;
  const int lane = tid & 63;
  const int wv = tid >> 6;
  const int wr = wv >> 2, wc = wv & 3;       // wave = 64x64 out tile
  const int fr = lane & 15;
  const int k8 = (lane >> 4) << 3;

  const int nwg = (int)gridDim.x;
  const int q8 = nwg >> 3, r8 = nwg & 7;
  const int x = (int)blockIdx.x & 7, idx = (int)blockIdx.x >> 3;
  const int wg = (x < r8 ? x * (q8 + 1) : r8 * (q8 + 1) + (x - r8) * q8) + idx;
  const int m0 = (wg / nbx) * 128, n0 = (wg % nbx) * 256;

  const int KT = K >> 6;

#define STAGE_AK(pt, kc, kt)                                                          \
  GLDS16(A + (size_t)(m0 + wv * 16 + fr) * K + (kt) * 64 + (kc) * 32 + k8,            \
         &Ab[pt][kc][wv * 512]);
#define STAGE_BK(pt, kc, kt)                                                          \
  { _Pragma("unroll") for (int u = 0; u < 2; ++u)                                     \
      GLDS16(W + (size_t)(n0 + (u * 8 + wv) * 16 + fr) * K + (kt) * 64 + (kc) * 32 + k8, \
             &Bb[pt][kc][(u * 8 + wv) * 512]); }

  f32x4 acc[4][4];
#pragma unroll
  for (int i = 0; i < 4; ++i)
#pragma unroll
    for (int j = 0; j < 4; ++j) acc[i][j] = (f32x4)0.0f;

  STAGE_AK(0, 0, 0) STAGE_BK(0, 0, 0)
  STAGE_AK(0, 1, 0) STAGE_BK(0, 1, 0)
  STAGE_AK(1, 0, 1) STAGE_BK(1, 0, 1)

  half8 af[4], bf[4];
  for (int t = 0; t < KT; ++t) {
    const int p = t & 1;
    if (t == KT - 1) { asm volatile("s_waitcnt vmcnt(0)" ::: "memory"); }
    else             { asm volatile("s_waitcnt vmcnt(3)" ::: "memory"); }
    __builtin_amdgcn_s_barrier();
#pragma unroll
    for (int kc = 0; kc < 2; ++kc) {
#pragma unroll
      for (int i = 0; i < 4; ++i)
        af[i] = *reinterpret_cast<const half8*>(&Ab[p][kc][(wr * 4 + i) * 512 + lane * 8]);
#pragma unroll
      for (int j = 0; j < 4; ++j)
        bf[j] = *reinterpret_cast<const half8*>(&Bb[p][kc][(wc * 4 + j) * 512 + lane * 8]);
      if (kc == 0) { if (t + 1 < KT) { STAGE_AK(p ^ 1, 1, t + 1) STAGE_BK(p ^ 1, 1, t + 1) } }
      else         { if (t + 2 < KT) { STAGE_AK(p, 0, t + 2)     STAGE_BK(p, 0, t + 2) } }
      __builtin_amdgcn_s_barrier();
      asm volatile("s_waitcnt lgkmcnt(0)" ::: "memory");
      __builtin_amdgcn_s_setprio(1);
#pragma unroll
      for (int i = 0; i < 4; ++i)
#pragma unroll
        for (int j = 0; j < 4; ++j)
          acc[i][j] = __builtin_amdgcn_mfma_f32_16x16x32_f16(af[i], bf[j], acc[i][j], 0, 0, 0);
      __builtin_amdgcn_s_setprio(0);
      __builtin_amdgcn_s_barrier();
    }
  }
#undef STAGE_AK
#undef STAGE_BK

  float bv[4];
#pragma unroll
  for (int nf = 0; nf < 4; ++nf) bv[nf] = bias[n0 + wc * 64 + nf * 16 + fr];
#pragma unroll
  for (int mf = 0; mf < 4; ++mf) {
#pragma unroll
    for (int r = 0; r < 4; ++r) {
      const int row = m0 + wr * 64 + mf * 16 + ((lane >> 4) << 2) + r;
      const size_t ro = (size_t)row * Nn;
#pragma unroll
      for (int nf = 0; nf < 4; ++nf) {
        const int col = n0 + wc * 64 + nf * 16 + fr;
        float u = acc[mf][nf][r] + bv[nf];
        if (GELU_EP) u = fast_gelu(u);
        if (RES) u += res_at(res, ro + col, RESH);
        if (OUT_HALF) ((_Float16*)Cout)[ro + col] = (_Float16)u;
        else          ((float*)Cout)[ro + col] = u;
      }
    }
  }
}

// ---------------- MFMA flash attention, QBLK=128, 8 waves (best) ----------------
__global__ __launch_bounds__(512) void mattn_kernel(const _Float16* __restrict__ qkv,
                                                    _Float16* __restrict__ ctx) {
  __shared__ __align__(16) _Float16 Ks[64][72];
  __shared__ __align__(16) _Float16 Vt[64][72];
  __shared__ __align__(16) _Float16 Ps[8][16][72];
  const int qt = blockIdx.x, h = blockIdx.y, b = blockIdx.z;
  const int tid = threadIdx.x;
  const int lane = tid & 63;
  const int w = tid >> 6;
  const int l15 = lane & 15;
  const int koff = (lane >> 4) * 8;

  const size_t qrow = (size_t)b * N_ + qt * 128 + w * 16 + l15;
  half8 qf0 = *reinterpret_cast<const half8*>(qkv + qrow * 3072 + h * 64 + koff);
  half8 qf1 = *reinterpret_cast<const half8*>(qkv + qrow * 3072 + h * 64 + 32 + koff);
  qf0 *= (_Float16)0.125f;
  qf1 *= (_Float16)0.125f;

  const int skey = tid >> 2;                  // valid for tid<256
  const int sch = (tid & 3) * 16;
  const int vcol = skey ^ ((tid & 3) << 4);

  float m_i[4], l_i[4];
  f32x4 oacc[4];
#pragma unroll
  for (int r = 0; r < 4; ++r) { m_i[r] = -3.0e38f; l_i[r] = 0.0f; }
#pragma unroll
  for (int jb = 0; jb < 4; ++jb) oacc[jb] = (f32x4)0.0f;

  for (int kt = 0; kt < 16; ++kt) {
    __syncthreads();
    if (tid < 256) {
      const _Float16* krow = qkv + ((size_t)b * N_ + kt * 64 + skey) * 3072 + 1024 + h * 64 + sch;
      half8 k0 = *reinterpret_cast<const half8*>(krow);
      half8 k1 = *reinterpret_cast<const half8*>(krow + 8);
      half8 v0 = *reinterpret_cast<const half8*>(krow + 1024);
      half8 v1 = *reinterpret_cast<const half8*>(krow + 1032);
      *reinterpret_cast<half8*>(&Ks[skey][sch]) = k0;
      *reinterpret_cast<half8*>(&Ks[skey][sch + 8]) = k1;
#pragma unroll
      for (int j = 0; j < 8; ++j) {
        Vt[sch + j][vcol] = v0[j];
        Vt[sch + 8 + j][vcol] = v1[j];
      }
    }
    __syncthreads();

    f32x4 sacc[4];
#pragma unroll
    for (int jb = 0; jb < 4; ++jb) sacc[jb] = (f32x4)0.0f;
#pragma unroll
    for (int jb = 0; jb < 4; ++jb) {
      half8 kfa = *reinterpret_cast<const half8*>(&Ks[jb * 16 + l15][koff]);
      half8 kfb = *reinterpret_cast<const half8*>(&Ks[jb * 16 + l15][32 + koff]);
      sacc[jb] = __builtin_amdgcn_mfma_f32_16x16x32_f16(qf0, kfa, sacc[jb], 0, 0, 0);
      sacc[jb] = __builtin_amdgcn_mfma_f32_16x16x32_f16(qf1, kfb, sacc[jb], 0, 0, 0);
    }

    float p[4][4];
#pragma unroll
    for (int r = 0; r < 4; ++r) {
      float mx = fmaxf(fmaxf(sacc[0][r], sacc[1][r]), fmaxf(sacc[2][r], sacc[3][r]));
#pragma unroll
      for (int mk = 1; mk < 16; mk <<= 1) mx = fmaxf(mx, __shfl_xor(mx, mk, 64));
      const float nm = fmaxf(m_i[r], mx);
      const float scale = __expf(m_i[r] - nm);
      float rs = 0.0f;
#pragma unroll
      for (int jb = 0; jb < 4; ++jb) { p[jb][r] = __expf(sacc[jb][r] - nm); rs += p[jb][r]; }
#pragma unroll
      for (int mk = 1; mk < 16; mk <<= 1) rs += __shfl_xor(rs, mk, 64);
      l_i[r] = l_i[r] * scale + rs;
      m_i[r] = nm;
#pragma unroll
      for (int jb = 0; jb < 4; ++jb) oacc[jb][r] *= scale;
    }

#pragma unroll
    for (int jb = 0; jb < 4; ++jb)
#pragma unroll
      for (int r = 0; r < 4; ++r)
        Ps[w][(lane >> 4) * 4 + r][jb * 16 + l15] = (_Float16)p[jb][r];

    half8 pf0 = *reinterpret_cast<const half8*>(&Ps[w][l15][koff]);
    half8 pf1 = *reinterpret_cast<const half8*>(&Ps[w][l15][32 + koff]);
#pragma unroll
    for (int jb = 0; jb < 4; ++jb) {
      half8 vf0 = *reinterpret_cast<const half8*>(&Vt[jb * 16 + l15][koff ^ (jb << 4)]);
      half8 vf1 = *reinterpret_cast<const half8*>(&Vt[jb * 16 + l15][(32 + koff) ^ (jb << 4)]);
      oacc[jb] = __builtin_amdgcn_mfma_f32_16x16x32_f16(pf0, vf0, oacc[jb], 0, 0, 0);
      oacc[jb] = __builtin_amdgcn_mfma_f32_16x16x32_f16(pf1, vf1, oacc[jb], 0, 0, 0);
    }
  }

#pragma unroll
  for (int jb = 0; jb < 4; ++jb)
#pragma unroll
    for (int r = 0; r < 4; ++r) {
      const size_t orow = (size_t)b * N_ + qt * 128 + w * 16 + (lane >> 4) * 4 + r;
      ctx[orow * 1024 + h * 64 + jb * 16 + l15] = (_Float16)(oacc[jb][r] / l_i[r]);
    }
}

// ---------------- score: mp[row] = dot(h_fp16[row], lin_w) ----------------
__global__ __launch_bounds__(256) void score_kernel(const _Float16* __restrict__ hbuf,
                                                    const float* __restrict__ lw,
                                                    float* __restrict__ mp) {
  __shared__ float sh[4];
  const int row = blockIdx.x, tid = threadIdx.x;
  const half4v v = reinterpret_cast<const half4v*>(hbuf + (size_t)row * D_)[tid];
  const float4 w = reinterpret_cast<const float4*>(lw)[tid];
  float s = (float)v[0] * w.x + (float)v[1] * w.y + (float)v[2] * w.z + (float)v[3] * w.w;
  s = waveSum(s);
  if ((tid & 63) == 0) sh[tid >> 6] = s;
  __syncthreads();
  if (tid == 0) mp[row] = sh[0] + sh[1] + sh[2] + sh[3];
}

// ---------------- lse over n of 2*(mp+g), gumbel computed inline ----------------
__global__ __launch_bounds__(256) void lse_kernel(const float* __restrict__ mp,
                                                  float* __restrict__ lse) {
  __shared__ float sh[4];
  const int row = blockIdx.x;          // k*8+b
  const int b = row & 7;
  const int tid = threadIdx.x;
  const unsigned j0 = (unsigned)row * 1024u + (unsigned)tid * 4u;
  const float4 mv = reinterpret_cast<const float4*>(mp + b * 1024)[tid];
  const float l0 = 2.0f * (gumbel_at(j0 + 0) + mv.x);
  const float l1 = 2.0f * (gumbel_at(j0 + 1) + mv.y);
  const float l2 = 2.0f * (gumbel_at(j0 + 2) + mv.z);
  const float l3 = 2.0f * (gumbel_at(j0 + 3) + mv.w);
  float mx = fmaxf(fmaxf(l0, l1), fmaxf(l2, l3));
  mx = waveMax(mx);
  if ((tid & 63) == 0) sh[tid >> 6] = mx;
  __syncthreads();
  mx = fmaxf(fmaxf(sh[0], sh[1]), fmaxf(sh[2], sh[3]));
  __syncthreads();
  float se = expf(l0 - mx) + expf(l1 - mx) + expf(l2 - mx) + expf(l3 - mx);
  se = waveSum(se);
  if ((tid & 63) == 0) sh[tid >> 6] = se;
  __syncthreads();
  if (tid == 0) lse[row] = mx + logf(sh[0] + sh[1] + sh[2] + sh[3]);
}

// ---------------- z two-stage, gumbel recomputed inline ----------------
__global__ __launch_bounds__(256) void zpart_kernel(const float* __restrict__ lse,
                                                    float* __restrict__ pb) {
  const int idx = blockIdx.x * 256 + threadIdx.x;   // b*1024+n
  const int kc = blockIdx.y;                        // 0..15
  const int b = idx >> 10;
  float best = -3.0e38f;
#pragma unroll 4
  for (int k = kc * 32; k < kc * 32 + 32; ++k) {
    const float gv = gumbel_at((unsigned)k * (unsigned)ROWS_ + (unsigned)idx);
    best = fmaxf(best, 2.0f * gv - lse[k * 8 + b]);
  }
  pb[(size_t)kc * ROWS_ + idx] = best;
}

__global__ __launch_bounds__(256) void zfin_kernel(const float* __restrict__ pb,
                                                   const float* __restrict__ mp,
                                                   float* __restrict__ z) {
  const int idx = blockIdx.x * 256 + threadIdx.x;
  float best = -3.0e38f;
#pragma unroll
  for (int kc = 0; kc < 16; ++kc) best = fmaxf(best, pb[(size_t)kc * ROWS_ + idx]);
  z[idx] = expf(2.0f * mp[idx] + best);
}

extern "C" void kernel_launch(void* const* d_in, const int* in_sizes, int n_in,
                              void* d_out, int out_size, void* d_ws, size_t ws_size,
                              hipStream_t stream) {
  (void)in_sizes; (void)n_in; (void)out_size; (void)ws_size;
  const float* f      = (const float*)d_in[0];
  const float* qkv_w  = (const float*)d_in[2];
  const float* qkv_b  = (const float*)d_in[3];
  const float* proj_w = (const float*)d_in[4];
  const float* proj_b = (const float*)d_in[5];
  const float* ln1_w  = (const float*)d_in[6];
  const float* ln1_b  = (const float*)d_in[7];
  const float* ln2_w  = (const float*)d_in[8];
  const float* ln2_b  = (const float*)d_in[9];
  const float* fc1_w  = (const float*)d_in[10];
  const float* fc1_b  = (const float*)d_in[11];
  const float* fc2_w  = (const float*)d_in[12];
  const float* fc2_b  = (const float*)d_in[13];
  const float* lin_w  = (const float*)d_in[14];
  float* out = (float*)d_out;

  // -------- workspace (f32 offsets; peak ~35.8M f32 = 143 MB) --------
  float* ws = (float*)d_ws;
  _Float16* wh = (_Float16*)d_ws;
  _Float16* QKVWH  = wh;                        // 3,145,728 h
  _Float16* PROJWH = wh + 3145728;              // 1,048,576 h
  _Float16* FC1WH  = wh + 4194304;              // 4,194,304 h
  _Float16* FC2WH  = wh + 8388608;              // 4,194,304 h -> ends f32 6,291,456
  float* MP  = ws + 6291456;                    // 8192
  float* LSE = ws + 6299648;                    // 4096
  _Float16* XH   = (_Float16*)(ws + 6303744);   // 8,388,608 h  -> ends 10,498,048
  _Float16* QKVH = (_Float16*)(ws + 10498048);  // 25,165,824 h (dead after attn)
  _Float16* CTXH = (_Float16*)(ws + 23080960);  // 8,388,608 h (dead after proj)
  _Float16* YH   = (_Float16*)(ws + 10498048);  // 33,554,432 h (reuses QKVH+CTXH)
  _Float16* F1H  = (_Float16*)(ws + 27275264);  // 8,388,608 h  -> ends 31,469,568
  _Float16* HbufH = (_Float16*)(ws + 31469568); // 8,388,608 h  -> ends 35,663,872
  float* PB   = ws + 35663872;                  // 131,072 f32 -> ends 35,794,944

  // fused weight conversion: 4 sources -> contiguous fp16 block (one launch)
  f2h4_kernel<<<12288, 256, 0, stream>>>(qkv_w, proj_w, fc1_w, fc2_w, QKVWH);

  ln_kernel<false><<<ROWS_, 256, 0, stream>>>(f, ln1_w, ln1_b, XH);
  // qkv: M=8192 N=3072 K=1024 -> 256x256, 384 blocks
  hgemm8w_kernel<false, false, false, true><<<384, 512, 0, stream>>>(XH, QKVWH, qkv_b, nullptr, QKVH, 3072, 1024, 12);
  // attention: QBLK=128, 8 waves, 1024 blocks
  mattn_kernel<<<dim3(8, 16, 8), 512, 0, stream>>>(QKVH, CTXH);
  // proj: M=8192 N=1024 K=1024 -> 128x256, 256 blocks; res = f (fp32), out fp16
  hgemm128_kernel<false, true, false, true><<<256, 512, 0, stream>>>(CTXH, PROJWH, proj_b, f, F1H, 1024, 1024, 4);
  ln_kernel<true><<<ROWS_, 256, 0, stream>>>(F1H, ln2_w, ln2_b, XH);
  // fc1: M=8192 N=4096 K=1024 -> 256x256, 512 blocks
  hgemm8w_kernel<true, false, false, true><<<512, 512, 0, stream>>>(XH, FC1WH, fc1_b, nullptr, YH, 4096, 1024, 16);
  // fc2: M=8192 N=1024 K=4096 -> 128x256, 256 blocks; res = F1H (fp16), out fp16
  hgemm128_kernel<false, true, true, true><<<256, 512, 0, stream>>>(YH, FC2WH, fc2_b, F1H, HbufH, 1024, 4096, 4);
  score_kernel<<<ROWS_, 256, 0, stream>>>(HbufH, lin_w, MP);
  lse_kernel<<<KD_ * B_, 256, 0, stream>>>(MP, LSE);
  zpart_kernel<<<dim3(ROWS_ / 256, 16), 256, 0, stream>>>(LSE, PB);
  zfin_kernel<<<ROWS_ / 256, 256, 0, stream>>>(PB, MP, out);
}